// Round 7
// baseline (6659.638 us; speedup 1.0000x reference)
//
#include <hip/hip_runtime.h>

#define TT 2048
#define EE 400
#define HH 200
#define G4 800
#define NS 20480
#define WMAX 10
#define HS 150
#define FD 20
#define GDIM 1220
#define NK 384
#define NA 128
#define OUTC 129

typedef unsigned int uint;
typedef unsigned short ushort;
typedef _Float16 h2_t __attribute__((ext_vector_type(2)));

__device__ __forceinline__ float bf2f(ushort u){ return __uint_as_float(((uint)u)<<16); }
__device__ __forceinline__ int binv(int x){
  int b=0;
  b += (x>=1); b += (x>=2); b += (x>=3); b += (x>=4);
  b += (x>=8); b += (x>=16); b += (x>=32); b += (x>=64);
  return b;
}
__device__ __forceinline__ float sigf(float x){ return 1.0f/(1.0f+__expf(-x)); }
__device__ __forceinline__ float tanhf_fast(float x){
  float t = __expf(-2.0f*fabsf(x));       // in (0,1], never overflows
  float r = (1.0f - t)/(1.0f + t);
  return copysignf(r, x);
}
__device__ __forceinline__ float sanit(float x){ return (fabsf(x) <= 1e30f) ? x : 0.f; }

__device__ __forceinline__ int sdot4(int a, int b, int c){
#if __has_builtin(__builtin_amdgcn_sdot4)
  return __builtin_amdgcn_sdot4(a, b, c, false);
#else
  int r = c;
  r += (int)(signed char)(a)     * (int)(signed char)(b);
  r += (int)(signed char)(a>>8)  * (int)(signed char)(b>>8);
  r += (int)(signed char)(a>>16) * (int)(signed char)(b>>16);
  r += (int)(signed char)(a>>24) * (int)(signed char)(b>>24);
  return r;
#endif
}

// max |w| over the real dims of this (row, half) 104-dim window
__device__ __forceinline__ float rowmax(const ushort* __restrict__ row, int half){
  float s = 1e-20f;
#pragma unroll
  for (int m=0;m<26;++m){
#pragma unroll
    for (int b=0;b<4;++b){
      int dim = 96*half + 4*m + b;
      bool real = (dim >= 100*half) && (dim < 100*half + 100);
      int dc = dim < 200 ? dim : 0;
      float w = bf2f(row[dc]);
      if (real) s = fmaxf(s, fabsf(w));
    }
  }
  return s;
}

// pack 4 int8-quantized weights (zeroing non-real dims) into one uint
__device__ __forceinline__ uint packw(const ushort* __restrict__ row, int half, int m, float inv){
  uint r = 0;
#pragma unroll
  for (int b=0;b<4;++b){
    int dim = 96*half + 4*m + b;
    bool real = (dim >= 100*half) && (dim < 100*half + 100);
    int dc = dim < 200 ? dim : 0;
    float w = real ? bf2f(row[dc]) : 0.f;
    int q = (int)rintf(w * inv);
    q = q < -127 ? -127 : (q > 127 ? 127 : q);
    r |= ((uint)(q & 0xff)) << (8*b);
  }
  return r;
}

// ---------------- K2: LSTM input projections (direct emb gather, f16 out) ----------------
__global__ void k_xproj(const int* __restrict__ tok, const ushort* __restrict__ emb,
                        const ushort* __restrict__ wf, const ushort* __restrict__ bfv,
                        const ushort* __restrict__ wb, const ushort* __restrict__ bbv,
                        _Float16* __restrict__ Xf, _Float16* __restrict__ Xb){
  __shared__ float x4[4][EE];
  __shared__ int tk[4];
  int t0 = blockIdx.x*4;
  if (threadIdx.x < 4) tk[threadIdx.x] = tok[t0+threadIdx.x];
  __syncthreads();
  for (int i = threadIdx.x; i < 4*EE; i += 256){
    int m = i / EE, e = i - m*EE;
    x4[m][e] = bf2f(emb[tk[m]*EE + e]);
  }
  __syncthreads();
  for (int tt = threadIdx.x; tt < 2*G4; tt += 256){
    int dir = (tt >= G4);
    int row = dir ? tt - G4 : tt;
    const ushort* wr = (dir ? wb : wf) + row*EE;
    float bias = bf2f((dir ? bbv : bfv)[row]);
    float a0=bias,a1=bias,a2=bias,a3=bias;
    for (int k=0;k<EE;k+=4){
      ushort4 wv = *(const ushort4*)(wr+k);
      float w0=bf2f(wv.x), w1=bf2f(wv.y), w2=bf2f(wv.z), w3=bf2f(wv.w);
      a0 += w0*x4[0][k] + w1*x4[0][k+1] + w2*x4[0][k+2] + w3*x4[0][k+3];
      a1 += w0*x4[1][k] + w1*x4[1][k+1] + w2*x4[1][k+2] + w3*x4[1][k+3];
      a2 += w0*x4[2][k] + w1*x4[2][k+1] + w2*x4[2][k+2] + w3*x4[2][k+3];
      a3 += w0*x4[3][k] + w1*x4[3][k+1] + w2*x4[3][k+2] + w3*x4[3][k+3];
    }
    _Float16* X = dir ? Xb : Xf;
    X[(t0+0)*G4+row]=(_Float16)a0; X[(t0+1)*G4+row]=(_Float16)a1;
    X[(t0+2)*G4+row]=(_Float16)a2; X[(t0+3)*G4+row]=(_Float16)a3;
  }
}

// ---------------- K3: sequential bi-LSTM (block0=fwd, block1=bwd) ----------------
// 832 threads, 800 active, 4 lanes per h-element j:
//   lane l = tid&3: half = l&1 (dim window), rowpair = l>>1.
//   rows: rA = rowpair*200 + j (gates i/f), rB = rA + 400 (gates g/o).
// Weights int8-quantized (per-row-window scale) packed into 52 named uints
// (52 VGPRs) -> fits the observed 128-VGPR budget with big margin.
// h double-buffered in LDS as int8 (208 B incl zero pad); one barrier/step.
__global__ __launch_bounds__(832, 4) void k_lstm(const ushort* __restrict__ whh_f,
                        const ushort* __restrict__ whh_b,
                        const _Float16* __restrict__ Xf, const _Float16* __restrict__ Xb,
                        float* __restrict__ hf, float* __restrict__ hb){
  const int tid = threadIdx.x;
  const int fwd = (blockIdx.x == 0);
  const ushort* whh = fwd ? whh_f : whh_b;
  const _Float16* X = fwd ? Xf : Xb;
  float* hout = fwd ? hf : hb;
  __shared__ __align__(16) uint hq2[2][52];   // two 208-B int8 h buffers (bytes 200..207 stay 0)
  const bool act = (tid < 800);
  const int j = tid >> 2;                 // 0..199
  const int jc = act ? j : 0;
  const int l = tid & 3;
  const int half = l & 1;
  const int rA = (l>>1)*HH + jc;          // gate i (rp0) / f (rp1)
  const int rB = rA + 2*HH;               // gate g (rp0) / o (rp1)
  const ushort* rowA = whh + rA*HH;
  const ushort* rowB = whh + rB*HH;
  const float sA = rowmax(rowA, half);
  const float sB = rowmax(rowB, half);
  const float invA = 127.f/sA, invB = 127.f/sB;
  const float scA = sA*(1.f/(127.f*127.f));
  const float scB = sB*(1.f/(127.f*127.f));

  uint wA0,wA1,wA2,wA3,wA4,wA5,wA6,wA7,wA8,wA9,wA10,wA11,wA12,
       wA13,wA14,wA15,wA16,wA17,wA18,wA19,wA20,wA21,wA22,wA23,wA24,wA25;
  uint wB0,wB1,wB2,wB3,wB4,wB5,wB6,wB7,wB8,wB9,wB10,wB11,wB12,
       wB13,wB14,wB15,wB16,wB17,wB18,wB19,wB20,wB21,wB22,wB23,wB24,wB25;
#define LW(n) wA##n = packw(rowA, half, n, invA); wB##n = packw(rowB, half, n, invB);
  LW(0) LW(1) LW(2) LW(3) LW(4) LW(5) LW(6) LW(7) LW(8) LW(9) LW(10) LW(11) LW(12)
  LW(13) LW(14) LW(15) LW(16) LW(17) LW(18) LW(19) LW(20) LW(21) LW(22) LW(23) LW(24) LW(25)
#undef LW

  if (tid < 104) ((uint*)hq2)[tid] = 0u;   // zero both buffers (incl pads)
  float c = 0.f;
  __syncthreads();
  for (int step=0; step<TT; ++step){
    int ts = fwd ? step : (TT-1-step);
    if (act){
      float xA = (half==0) ? (float)X[ts*G4 + rA] : 0.f;
      float xB = (half==0) ? (float)X[ts*G4 + rB] : 0.f;
      const uint* hb_ = hq2[step&1] + 24*half;   // byte offset 96*half
      int dA=0, dB=0;
#define DS(n) { uint u = hb_[n]; dA = sdot4((int)wA##n,(int)u,dA); dB = sdot4((int)wB##n,(int)u,dB); }
      DS(0) DS(1) DS(2) DS(3) DS(4) DS(5) DS(6) DS(7) DS(8) DS(9) DS(10) DS(11) DS(12)
      DS(13) DS(14) DS(15) DS(16) DS(17) DS(18) DS(19) DS(20) DS(21) DS(22) DS(23) DS(24) DS(25)
#undef DS
      float aA = (float)dA * scA + xA;
      float aB = (float)dB * scB + xB;
      // reduce across dim halves (partner lane = tid^1)
      aA += __shfl_xor(aA, 1, 64);
      aB += __shfl_xor(aB, 1, 64);
      // exchange between rowpairs (partner lane = tid^2)
      float tA = __shfl_xor(aA, 2, 64);
      float tB = __shfl_xor(aB, 2, 64);
      float iV = (l<2) ? aA : tA;
      float gV = (l<2) ? aB : tB;
      float fV = (l<2) ? tA : aA;
      float oV = (l<2) ? tB : aB;
      c = sigf(fV)*c + sigf(iV)*tanhf_fast(gV);
      float h = sigf(oV)*tanhf_fast(c);
      if (l==0){
        hout[ts*HH + j] = h;
        int q = (int)rintf(h*127.f);
        q = q<-127?-127:(q>127?127:q);
        ((unsigned char*)hq2[(step+1)&1])[j] = (unsigned char)(q & 0xff);
      }
    }
    __syncthreads();
  }
}

// ---------------- K4: token attention-score MLP ----------------
__global__ void k_attn(const float* __restrict__ hf, const float* __restrict__ hb,
    const ushort* w1, const ushort* b1, const ushort* w2, const ushort* b2,
    const ushort* w3, const ushort* b3, float* __restrict__ attns){
  __shared__ float s[2*HH];
  __shared__ float h1[HS], h2[HS];
  int t = blockIdx.x;
  for (int k=threadIdx.x;k<2*HH;k+=256)
    s[k] = (k<HH) ? hf[t*HH+k] : hb[t*HH + (k-HH)];
  __syncthreads();
  int o = threadIdx.x;
  if (o < HS){
    float acc = bf2f(b1[o]);
    const ushort* wr = w1 + o*2*HH;
    for (int k=0;k<2*HH;k+=4){
      ushort4 wv = *(const ushort4*)(wr+k);
      acc += bf2f(wv.x)*s[k] + bf2f(wv.y)*s[k+1] + bf2f(wv.z)*s[k+2] + bf2f(wv.w)*s[k+3];
    }
    h1[o] = fmaxf(acc, 0.f);
  }
  __syncthreads();
  if (o < HS){
    float acc = bf2f(b2[o]);
    const ushort* wr = w2 + o*HS;
    for (int k=0;k<HS;k+=2) acc += bf2f(wr[k])*h1[k] + bf2f(wr[k+1])*h1[k+1];
    h2[o] = fmaxf(acc, 0.f);
  }
  __syncthreads();
  if (o == 0){
    float acc = bf2f(b3[0]);
    for (int k=0;k<HS;k++) acc += bf2f(w3[k])*h2[k];
    attns[t] = acc;
  }
}

// ---------------- K5: span features + mention MLP (8 spans/block) ----------------
__global__ void k_ment(const int* __restrict__ sstart, const int* __restrict__ send,
    const int* __restrict__ tok,
    const float* __restrict__ hf, const float* __restrict__ hb,
    const ushort* __restrict__ emb, const float* __restrict__ attns,
    const ushort* wemb,
    const ushort* w1, const ushort* b1, const ushort* w2, const ushort* b2,
    const ushort* w3, const ushort* b3, float* __restrict__ si){
  __shared__ __align__(16) float G[8][GDIM];
  __shared__ float H1[8][152], H2[8][152];
  __shared__ float aw[8][WMAX];
  __shared__ int stok[8][WMAX];
  __shared__ int sst[8], sen[8], sbin[8];
  int s0 = blockIdx.x*8;
  if (threadIdx.x < 8){
    int sp = threadIdx.x;
    int st = sstart[s0+sp], en = send[s0+sp];
    sst[sp]=st; sen[sp]=en;
    int width = en - st + 1;
    sbin[sp] = binv(width);
    float lg[WMAX]; float mx = -1e30f;
    for (int wt=0; wt<WMAX; ++wt){
      int idx = st + wt; if (idx > TT-1) idx = TT-1;
      float l = (wt < width) ? attns[idx] : -1e9f;
      lg[wt] = l; mx = fmaxf(mx, l);
    }
    float den = 0.f;
    for (int wt=0; wt<WMAX; ++wt){ lg[wt] = __expf(lg[wt]-mx); den += lg[wt]; }
    float inv = 1.f/den;
    for (int wt=0; wt<WMAX; ++wt) aw[sp][wt] = lg[wt]*inv;
  }
  if (threadIdx.x < 8*WMAX){
    int sp = threadIdx.x / WMAX, wt = threadIdx.x - sp*WMAX;
    int idx = sstart[s0+sp] + wt; if (idx > TT-1) idx = TT-1;
    stok[sp][wt] = tok[idx];
  }
  __syncthreads();
  for (int i = threadIdx.x; i < 8*GDIM; i += 256){
    int sp = i / GDIM, f = i - sp*GDIM;
    int st = sst[sp], en = sen[sp];
    float v;
    if (f < HH) v = hf[st*HH + f];
    else if (f < 2*HH) v = hb[st*HH + (f-HH)];
    else if (f < 3*HH) v = hf[en*HH + (f-2*HH)];
    else if (f < 4*HH) v = hb[en*HH + (f-3*HH)];
    else if (f < 4*HH + EE){
      int e = f - 4*HH;
      float acc = 0.f;
      for (int wt=0; wt<WMAX; ++wt)
        acc += aw[sp][wt] * bf2f(emb[stok[sp][wt]*EE + e]);
      v = acc;
    } else {
      v = bf2f(wemb[sbin[sp]*FD + (f - (4*HH+EE))]);
    }
    G[sp][f] = v;
  }
  __syncthreads();
  for (int tt = threadIdx.x; tt < 8*HS; tt += 256){
    int sp = tt & 7, o = tt >> 3;
    float acc = bf2f(b1[o]);
    const ushort* wr = w1 + o*GDIM;
    for (int k=0;k<GDIM;k+=4){
      ushort4 wv = *(const ushort4*)(wr+k);
      acc += bf2f(wv.x)*G[sp][k] + bf2f(wv.y)*G[sp][k+1]
           + bf2f(wv.z)*G[sp][k+2] + bf2f(wv.w)*G[sp][k+3];
    }
    H1[sp][o] = fmaxf(acc, 0.f);
  }
  __syncthreads();
  for (int tt = threadIdx.x; tt < 8*HS; tt += 256){
    int sp = tt & 7, o = tt >> 3;
    float acc = bf2f(b2[o]);
    const ushort* wr = w2 + o*HS;
    for (int k=0;k<HS;k+=2) acc += bf2f(wr[k])*H1[sp][k] + bf2f(wr[k+1])*H1[sp][k+1];
    H2[sp][o] = fmaxf(acc, 0.f);
  }
  __syncthreads();
  if (threadIdx.x < 8){
    int sp = threadIdx.x;
    float acc = bf2f(b3[0]);
    for (int k=0;k<HS;k++) acc += bf2f(w3[k])*H2[sp][k];
    si[s0+sp] = sanit(acc);
  }
}

// ---------------- K6: top-384 + index-ordered compaction (single block) ----------------
__global__ __launch_bounds__(1024) void k_select(const float* __restrict__ si,
    const int* __restrict__ sstart, const int* __restrict__ send,
    uint* __restrict__ keysb, int* __restrict__ keep, float* __restrict__ sk,
    int* __restrict__ stk, int* __restrict__ enk){
  __shared__ uint hist[256];
  __shared__ uint sG[1024], sE[1024];
  __shared__ uint bc[2];
  int tid = threadIdx.x;
  if (tid < NK){ keep[tid]=0; sk[tid]=0.f; stk[tid]=0; enk[tid]=0; }
  for (int i=tid;i<NS;i+=1024){
    uint u = __float_as_uint(si[i]);
    uint m = (u & 0x80000000u) ? ~u : (u | 0x80000000u);  // order-preserving map
    keysb[i] = m;
  }
  __syncthreads();
  uint prefix=0, mask=0; int K = NK;
  for (int p=3;p>=0;--p){
    int sh = p*8;
    if (tid<256) hist[tid]=0;
    __syncthreads();
    for (int i=tid;i<NS;i+=1024){
      uint m = keysb[i];
      if ((m & mask) == prefix) atomicAdd(&hist[(m>>sh)&255u], 1u);
    }
    __syncthreads();
    if (tid==0){
      uint cum=0;
      bc[0]=0; bc[1]=(uint)K;
      for (int b=255; b>=0; --b){
        uint c = hist[b];
        if ((uint)K <= cum + c){ bc[0]=(uint)b; bc[1]=(uint)(K - (int)cum); break; }
        cum += c;
      }
    }
    __syncthreads();
    prefix |= bc[0] << sh;
    mask |= 0xFFu << sh;
    K = (int)bc[1];
    __syncthreads();
  }
  const uint V = prefix; const uint Eneed = (uint)K;
  int base = tid*20;
  uint cg=0, ce=0;
  for (int r=0;r<20;++r){
    uint m = keysb[base+r];
    cg += (m > V); ce += (m == V);
  }
  sG[tid]=cg; sE[tid]=ce;
  __syncthreads();
  for (int off=1; off<1024; off<<=1){
    uint aG=0,aE=0;
    if (tid>=off){ aG=sG[tid-off]; aE=sE[tid-off]; }
    __syncthreads();
    if (tid>=off){ sG[tid]+=aG; sE[tid]+=aE; }
    __syncthreads();
  }
  uint gbase = sG[tid]-cg, ebase = sE[tid]-ce;
  uint gseen=0, eseen=0;
  for (int r=0;r<20;++r){
    int i = base+r;
    uint m = keysb[i];
    if (m > V){
      uint eb = ebase+eseen; if (eb > Eneed) eb = Eneed;
      uint pos = gbase + gseen + eb;
      if (pos < NK){ keep[pos]=i; sk[pos]=si[i]; stk[pos]=sstart[i]; enk[pos]=send[i]; }
      gseen++;
    } else if (m == V){
      uint eb = ebase + eseen;
      if (eb < Eneed){
        uint pos = gbase + gseen + eb;
        if (pos < NK){ keep[pos]=i; sk[pos]=si[i]; stk[pos]=sstart[i]; enk[pos]=send[i]; }
      }
      eseen++;
    }
  }
}

// ---------------- K7: rebuild g for kept spans ----------------
__global__ void k_gk(const int* __restrict__ keep, const int* __restrict__ tok,
    const float* __restrict__ hf, const float* __restrict__ hb,
    const ushort* __restrict__ emb, const float* __restrict__ attns,
    const ushort* wemb, const int* __restrict__ sstart, const int* __restrict__ send,
    float* __restrict__ gk){
  __shared__ float aw[WMAX];
  __shared__ int stok1[WMAX];
  __shared__ int sstv, senv, sbinv;
  int b = blockIdx.x;
  if (threadIdx.x == 0){
    int s = keep[b]; s = s < 0 ? 0 : (s >= NS ? NS-1 : s);
    int st = sstart[s], en = send[s];
    sstv=st; senv=en;
    int width = en-st+1;
    sbinv = binv(width);
    float lg[WMAX]; float mx=-1e30f;
    for (int wt=0;wt<WMAX;++wt){
      int idx = st+wt; if (idx>TT-1) idx=TT-1;
      float l = (wt<width)? attns[idx] : -1e9f;
      lg[wt]=l; mx=fmaxf(mx,l);
    }
    float den=0.f;
    for (int wt=0;wt<WMAX;++wt){ lg[wt]=__expf(lg[wt]-mx); den+=lg[wt]; }
    float inv=1.f/den;
    for (int wt=0;wt<WMAX;++wt) aw[wt]=lg[wt]*inv;
  }
  if (threadIdx.x < WMAX){
    int s = keep[b]; s = s < 0 ? 0 : (s >= NS ? NS-1 : s);
    int idx = sstart[s] + threadIdx.x; if (idx>TT-1) idx=TT-1;
    stok1[threadIdx.x] = tok[idx];
  }
  __syncthreads();
  int st=sstv, en=senv;
  for (int f=threadIdx.x; f<GDIM; f+=256){
    float v;
    if (f < HH) v = hf[st*HH + f];
    else if (f < 2*HH) v = hb[st*HH + (f-HH)];
    else if (f < 3*HH) v = hf[en*HH + (f-2*HH)];
    else if (f < 4*HH) v = hb[en*HH + (f-3*HH)];
    else if (f < 4*HH + EE){
      int e = f - 4*HH;
      float acc = 0.f;
      for (int wt=0; wt<WMAX; ++wt)
        acc += aw[wt] * bf2f(emb[stok1[wt]*EE + e]);
      v = acc;
    } else {
      v = bf2f(wemb[sbinv*FD + (f - (4*HH+EE))]);
    }
    gk[b*GDIM + f] = v;
  }
}

// ---------------- K8a: P[i]=w1a.gk[i], Q[i]=w1b.gk[i]; also eps column ----------------
__global__ void k_pq(const float* __restrict__ gk, const ushort* __restrict__ w1,
                     float* __restrict__ P, float* __restrict__ Q, float* __restrict__ out){
  __shared__ __align__(16) float gi[GDIM];
  int i = blockIdx.x, which = blockIdx.y;
  for (int k=threadIdx.x;k<GDIM;k+=256) gi[k]=gk[i*GDIM+k];
  __syncthreads();
  if (which==0 && threadIdx.x==0) out[i*OUTC + NA] = 0.0f;   // eps column
  int o = threadIdx.x;
  if (o < HS){
    const ushort* wr = w1 + o*3680 + which*GDIM;
    float acc=0.f;
    for (int k=0;k<GDIM;k+=4){
      ushort4 wv = *(const ushort4*)(wr+k);
      acc += bf2f(wv.x)*gi[k]+bf2f(wv.y)*gi[k+1]+bf2f(wv.z)*gi[k+2]+bf2f(wv.w)*gi[k+3];
    }
    (which? Q : P)[i*HS+o] = acc;
  }
}

// ---------------- K8b: pair MLP (decomposed layer-1), 16 antecedents/block ----------------
__global__ void k_pair(const float* __restrict__ gk, const float* __restrict__ P,
    const float* __restrict__ Q, const float* __restrict__ sk,
    const int* __restrict__ stk, const int* __restrict__ enk,
    const ushort* w1, const ushort* b1, const ushort* w2, const ushort* b2,
    const ushort* w3, const ushort* b3, const ushort* demb, float* __restrict__ out){
  __shared__ __align__(16) float gi[GDIM];
  __shared__ float Pi[152];
  __shared__ float Dall[9*HS];
  __shared__ __align__(16) float GIJ[8][GDIM];
  __shared__ float H1[8][152], H2[8][152];
  __shared__ int jcA[16], dbA[16], vA[16];
  __shared__ float skj[16];
  int i = blockIdx.x;
  int d0 = blockIdx.y*16;
  // whole-block skip: all 16 antecedents invalid
  if (i - 1 - d0 < 0){
    for (int d = threadIdx.x; d < 16; d += 256) out[i*OUTC + d0 + d] = -1e9f;
    return;
  }
  for (int k=threadIdx.x;k<GDIM;k+=256) gi[k]=gk[i*GDIM+k];
  for (int o=threadIdx.x;o<HS;o+=256) Pi[o]=P[i*HS+o];
  if (threadIdx.x < 16){
    int dcol = d0 + threadIdx.x;
    int j = i - 1 - dcol;
    int jc = j<0?0:j;
    vA[threadIdx.x]=(j>=0);
    jcA[threadIdx.x]=jc;
    dbA[threadIdx.x]=binv(enk[i]-stk[jc]);
    skj[threadIdx.x]=sk[jc];
  }
  for (int tt=threadIdx.x; tt<9*HS; tt+=256){
    int o = tt/9, b = tt - (tt/9)*9;
    float acc = bf2f(b1[o]);
    const ushort* wr = w1 + o*3680 + 3660;
    const ushort* de = demb + b*FD;
    for (int k=0;k<FD;k++) acc += bf2f(wr[k])*bf2f(de[k]);
    Dall[b*HS+o] = acc;
  }
  __syncthreads();
  float ski = sk[i];
  for (int dt=0; dt<2; ++dt){
    if (i - 1 - (d0 + dt*8) < 0){
      if (threadIdx.x < 8) out[i*OUTC + d0 + dt*8 + threadIdx.x] = -1e9f;
      continue;
    }
    __syncthreads();
    for (int idx=threadIdx.x; idx<8*GDIM; idx+=256){
      int dd = idx / GDIM, k = idx - dd*GDIM;
      GIJ[dd][k] = gi[k]*gk[jcA[dt*8+dd]*GDIM + k];
    }
    __syncthreads();
    {
      int dd = threadIdx.x & 7, og = threadIdx.x >> 3;
      for (int o=og; o<HS; o+=32){
        const ushort* wr = w1 + o*3680 + 2*GDIM;
        float acc = 0.f;
        for (int k=0;k<GDIM;k+=4){
          ushort4 wv = *(const ushort4*)(wr+k);
          float4 gv = *(const float4*)&GIJ[dd][k];
          acc += bf2f(wv.x)*gv.x + bf2f(wv.y)*gv.y + bf2f(wv.z)*gv.z + bf2f(wv.w)*gv.w;
        }
        int d = dt*8+dd;
        acc += Pi[o] + Q[jcA[d]*HS+o] + Dall[dbA[d]*HS+o];
        H1[dd][o] = fmaxf(acc, 0.f);
      }
    }
    __syncthreads();
    {
      int dd = threadIdx.x & 7, og = threadIdx.x >> 3;
      for (int o=og;o<HS;o+=32){
        float acc = bf2f(b2[o]);
        const ushort* wr = w2 + o*HS;
        for (int k=0;k<HS;k+=2) acc += bf2f(wr[k])*H1[dd][k] + bf2f(wr[k+1])*H1[dd][k+1];
        H2[dd][o]=fmaxf(acc,0.f);
      }
    }
    __syncthreads();
    if (threadIdx.x < 8){
      int dd = threadIdx.x;
      float acc = bf2f(b3[0]);
      for (int k=0;k<HS;k++) acc += bf2f(w3[k])*H2[dd][k];
      int d = dt*8+dd;
      float raw = sanit(ski + skj[d] + acc);
      float v = vA[d] ? raw : -1e9f;
      out[i*OUTC + d0 + d] = v;
    }
  }
}

extern "C" void kernel_launch(void* const* d_in, const int* in_sizes, int n_in,
                              void* d_out, int out_size, void* d_ws, size_t ws_size,
                              hipStream_t stream){
  (void)in_sizes; (void)n_in; (void)out_size; (void)ws_size;
  const int*    tok   = (const int*)d_in[0];
  const int*    sst   = (const int*)d_in[1];
  const int*    sen   = (const int*)d_in[2];
  const ushort* emb   = (const ushort*)d_in[3];
  const ushort* wih_f = (const ushort*)d_in[4];
  const ushort* whh_f = (const ushort*)d_in[5];
  const ushort* b_f   = (const ushort*)d_in[6];
  const ushort* wih_b = (const ushort*)d_in[7];
  const ushort* whh_b = (const ushort*)d_in[8];
  const ushort* b_b   = (const ushort*)d_in[9];
  const ushort* aw1=(const ushort*)d_in[10]; const ushort* ab1=(const ushort*)d_in[11];
  const ushort* aw2=(const ushort*)d_in[12]; const ushort* ab2=(const ushort*)d_in[13];
  const ushort* aw3=(const ushort*)d_in[14]; const ushort* ab3=(const ushort*)d_in[15];
  const ushort* wemb=(const ushort*)d_in[16];
  const ushort* mw1=(const ushort*)d_in[17]; const ushort* mb1=(const ushort*)d_in[18];
  const ushort* mw2=(const ushort*)d_in[19]; const ushort* mb2=(const ushort*)d_in[20];
  const ushort* mw3=(const ushort*)d_in[21]; const ushort* mb3=(const ushort*)d_in[22];
  const ushort* demb=(const ushort*)d_in[23];
  const ushort* pw1=(const ushort*)d_in[24]; const ushort* pb1=(const ushort*)d_in[25];
  const ushort* pw2=(const ushort*)d_in[26]; const ushort* pb2=(const ushort*)d_in[27];
  const ushort* pw3=(const ushort*)d_in[28]; const ushort* pb3=(const ushort*)d_in[29];
  float* out = (float*)d_out;

  float* ws     = (float*)d_ws;
  float* hfw    = ws;                       // 409600
  float* hbw    = hfw + TT*HH;              // 409600
  float* attns  = hbw + TT*HH;              // 2048
  float* si     = attns + TT;               // 20480
  float* sk     = si + NS;                  // 384
  float* Pb     = sk + NK;                  // 57600
  float* Qb     = Pb + NK*HS;               // 57600
  float* gkw    = Qb + NK*HS;               // 468480
  _Float16* Xf  = (_Float16*)(gkw + NK*GDIM); // 1638400 halves
  _Float16* Xb  = Xf + TT*G4;                 // 1638400 halves
  int*   keep   = (int*)(Xb + TT*G4);       // 384
  int*   stk    = keep + NK;                // 384
  int*   enk    = stk + NK;                 // 384
  uint*  keysb  = (uint*)(enk + NK);        // 20480
  // total ~12.34 MB of d_ws

  k_xproj<<<TT/4,256,0,stream>>>(tok, emb, wih_f, b_f, wih_b, b_b, Xf, Xb);
  k_lstm<<<2,832,0,stream>>>(whh_f, whh_b, Xf, Xb, hfw, hbw);
  k_attn<<<TT,256,0,stream>>>(hfw,hbw,aw1,ab1,aw2,ab2,aw3,ab3,attns);
  k_ment<<<NS/8,256,0,stream>>>(sst,sen,tok,hfw,hbw,emb,attns,wemb,mw1,mb1,mw2,mb2,mw3,mb3,si);
  k_select<<<1,1024,0,stream>>>(si,sst,sen,keysb,keep,sk,stk,enk);
  k_gk<<<NK,256,0,stream>>>(keep,tok,hfw,hbw,emb,attns,wemb,sst,sen,gkw);
  k_pq<<<dim3(NK,2),256,0,stream>>>(gkw,pw1,Pb,Qb,out);
  k_pair<<<dim3(NK,8),256,0,stream>>>(gkw,Pb,Qb,sk,stk,enk,pw1,pb1,pw2,pb2,pw3,pb3,demb,out);
}

// Round 8
// 4993.338 us; speedup vs baseline: 1.3337x; 1.3337x over previous
//
#include <hip/hip_runtime.h>

#define TT 2048
#define EE 400
#define HH 200
#define G4 800
#define NS 20480
#define WMAX 10
#define HS 150
#define FD 20
#define GDIM 1220
#define NK 384
#define NA 128
#define OUTC 129

typedef unsigned int uint;
typedef unsigned short ushort;

__device__ __forceinline__ float bf2f(ushort u){ return __uint_as_float(((uint)u)<<16); }
__device__ __forceinline__ int binv(int x){
  int b=0;
  b += (x>=1); b += (x>=2); b += (x>=3); b += (x>=4);
  b += (x>=8); b += (x>=16); b += (x>=32); b += (x>=64);
  return b;
}
__device__ __forceinline__ float sigf(float x){ return 1.0f/(1.0f+__expf(-x)); }
__device__ __forceinline__ float tanhf_fast(float x){
  float t = __expf(-2.0f*fabsf(x));       // in (0,1], never overflows
  float r = (1.0f - t)/(1.0f + t);
  return copysignf(r, x);
}
__device__ __forceinline__ float sanit(float x){ return (fabsf(x) <= 1e30f) ? x : 0.f; }

__device__ __forceinline__ int sdot4(int a, int b, int c){
#if __has_builtin(__builtin_amdgcn_sdot4)
  return __builtin_amdgcn_sdot4(a, b, c, false);
#else
  int r = c;
  r += (int)(signed char)(a)     * (int)(signed char)(b);
  r += (int)(signed char)(a>>8)  * (int)(signed char)(b>>8);
  r += (int)(signed char)(a>>16) * (int)(signed char)(b>>16);
  r += (int)(signed char)(a>>24) * (int)(signed char)(b>>24);
  return r;
#endif
}

// pack 4 dims (4n..4n+3) of a bf16 row into one int8 uint
__device__ __forceinline__ uint p4(const ushort* __restrict__ row, int n, float inv){
  uint r = 0;
#pragma unroll
  for (int b=0;b<4;++b){
    float w = bf2f(row[4*n+b]);
    int q = (int)rintf(w * inv);
    q = q < -127 ? -127 : (q > 127 ? 127 : q);
    r |= ((uint)(q & 0xff)) << (8*b);
  }
  return r;
}

template<int STRQ>
__device__ __forceinline__ void pack25(uint4* __restrict__ wp,
    const ushort* r0, const ushort* r1, const ushort* r2, const ushort* r3,
    float i0, float i1, float i2, float i3){
#pragma unroll
  for (int n=0;n<25;++n){
    uint4 wv;
    wv.x = p4(r0,n,i0); wv.y = p4(r1,n,i1); wv.z = p4(r2,n,i2); wv.w = p4(r3,n,i3);
    wp[n*STRQ] = wv;
  }
}

struct I4 { int d0,d1,d2,d3; };

template<int STRQ>
__device__ __forceinline__ I4 dot25(const uint4* __restrict__ wp,
    uint4 hA, uint4 hB, uint4 hC, uint4 hD, uint4 hE, uint4 hF, uint hG){
  I4 a; a.d0=0; a.d1=0; a.d2=0; a.d3=0;
#define DD(n,hu) { uint4 wv = wp[(n)*STRQ]; \
  a.d0=sdot4((int)wv.x,(int)(hu),a.d0); a.d1=sdot4((int)wv.y,(int)(hu),a.d1); \
  a.d2=sdot4((int)wv.z,(int)(hu),a.d2); a.d3=sdot4((int)wv.w,(int)(hu),a.d3); }
  DD(0,hA.x) DD(1,hA.y) DD(2,hA.z) DD(3,hA.w)
  DD(4,hB.x) DD(5,hB.y) DD(6,hB.z) DD(7,hB.w)
  DD(8,hC.x) DD(9,hC.y) DD(10,hC.z) DD(11,hC.w)
  DD(12,hD.x) DD(13,hD.y) DD(14,hD.z) DD(15,hD.w)
  DD(16,hE.x) DD(17,hE.y) DD(18,hE.z) DD(19,hE.w)
  DD(20,hF.x) DD(21,hF.y) DD(22,hF.z) DD(23,hF.w)
  DD(24,hG)
#undef DD
  return a;
}

// ---------------- K2: LSTM input projections (direct emb gather, f16 out) ----------------
__global__ void k_xproj(const int* __restrict__ tok, const ushort* __restrict__ emb,
                        const ushort* __restrict__ wf, const ushort* __restrict__ bfv,
                        const ushort* __restrict__ wb, const ushort* __restrict__ bbv,
                        _Float16* __restrict__ Xf, _Float16* __restrict__ Xb){
  __shared__ float x4[4][EE];
  __shared__ int tk[4];
  int t0 = blockIdx.x*4;
  if (threadIdx.x < 4) tk[threadIdx.x] = tok[t0+threadIdx.x];
  __syncthreads();
  for (int i = threadIdx.x; i < 4*EE; i += 256){
    int m = i / EE, e = i - m*EE;
    x4[m][e] = bf2f(emb[tk[m]*EE + e]);
  }
  __syncthreads();
  for (int tt = threadIdx.x; tt < 2*G4; tt += 256){
    int dir = (tt >= G4);
    int row = dir ? tt - G4 : tt;
    const ushort* wr = (dir ? wb : wf) + row*EE;
    float bias = bf2f((dir ? bbv : bfv)[row]);
    float a0=bias,a1=bias,a2=bias,a3=bias;
    for (int k=0;k<EE;k+=4){
      ushort4 wv = *(const ushort4*)(wr+k);
      float w0=bf2f(wv.x), w1=bf2f(wv.y), w2=bf2f(wv.z), w3=bf2f(wv.w);
      a0 += w0*x4[0][k] + w1*x4[0][k+1] + w2*x4[0][k+2] + w3*x4[0][k+3];
      a1 += w0*x4[1][k] + w1*x4[1][k+1] + w2*x4[1][k+2] + w3*x4[1][k+3];
      a2 += w0*x4[2][k] + w1*x4[2][k+1] + w2*x4[2][k+2] + w3*x4[2][k+3];
      a3 += w0*x4[3][k] + w1*x4[3][k+1] + w2*x4[3][k+2] + w3*x4[3][k+3];
    }
    _Float16* X = dir ? Xb : Xf;
    X[(t0+0)*G4+row]=(_Float16)a0; X[(t0+1)*G4+row]=(_Float16)a1;
    X[(t0+2)*G4+row]=(_Float16)a2; X[(t0+3)*G4+row]=(_Float16)a3;
  }
}

// ---------------- K3: sequential bi-LSTM (block0=fwd, block1=bwd) ----------------
// Weights int8 in LDS (160,000 B), stored in exact wave access order ->
// conflict-free coalesced ds_read_b128 with immediate offsets. 448 threads,
// 400 active: 2 lanes per h-element j (lane = dim half); each lane computes
// all 4 gate rows over its 100-dim half: 25 b128 weight reads + 100 sdot4.
// h int8 double-buffered (broadcast reads); one barrier per step.
// No persistent per-thread state beyond ~12 regs -> nothing to spill.
__global__ __launch_bounds__(448) void k_lstm(const ushort* __restrict__ whh_f,
                        const ushort* __restrict__ whh_b,
                        const _Float16* __restrict__ Xf, const _Float16* __restrict__ Xb,
                        float* __restrict__ hf, float* __restrict__ hb){
  __shared__ __align__(16) uint4 wlds4[10000];  // 160,000 B quantized weights
  __shared__ __align__(16) uint  hq[112];       // 2 x 224-B int8 h buffers (28dw halves)
  const int tid = threadIdx.x;
  const int fwd = (blockIdx.x == 0);
  const ushort* whh = fwd ? whh_f : whh_b;
  const _Float16* X = fwd ? Xf : Xb;
  float* hout = fwd ? hf : hb;
  const bool act = (tid < 400);
  const int j = tid >> 1;                // 0..199
  const int half = tid & 1;              // dim half
  const int w = tid >> 6;                // wave id 0..6
  const int l = tid & 63;
  const bool fullw = (w < 6);
  // lane's weight slot base (uint4 units): waves 0..5 full blocks, wave 6 tail(16 lanes)
  const int baseq = fullw ? (w*1600 + l) : (9600 + l);

  float mx0=1e-20f, mx1=1e-20f, mx2=1e-20f, mx3=1e-20f;
  if (act){
    const ushort* r0 = whh + (0*HH + j)*HH + half*100;
    const ushort* r1 = whh + (1*HH + j)*HH + half*100;
    const ushort* r2 = whh + (2*HH + j)*HH + half*100;
    const ushort* r3 = whh + (3*HH + j)*HH + half*100;
    for (int d=0; d<100; ++d){
      mx0 = fmaxf(mx0, fabsf(bf2f(r0[d])));
      mx1 = fmaxf(mx1, fabsf(bf2f(r1[d])));
      mx2 = fmaxf(mx2, fabsf(bf2f(r2[d])));
      mx3 = fmaxf(mx3, fabsf(bf2f(r3[d])));
    }
    float i0=127.f/mx0, i1=127.f/mx1, i2=127.f/mx2, i3=127.f/mx3;
    if (fullw) pack25<64>(wlds4 + baseq, r0,r1,r2,r3, i0,i1,i2,i3);
    else       pack25<16>(wlds4 + baseq, r0,r1,r2,r3, i0,i1,i2,i3);
  }
  const float sc0 = mx0*(1.f/16129.f), sc1 = mx1*(1.f/16129.f);
  const float sc2 = mx2*(1.f/16129.f), sc3 = mx3*(1.f/16129.f);
  if (tid < 112) hq[tid] = 0u;
  float c = 0.f;
  __syncthreads();
  for (int step=0; step<TT; ++step){
    int ts = fwd ? step : (TT-1-step);
    if (act){
      // x inputs for all 4 gates of row j (independent of h)
      float x0 = (float)X[ts*G4 + 0*HH + j];
      float x1 = (float)X[ts*G4 + 1*HH + j];
      float x2 = (float)X[ts*G4 + 2*HH + j];
      float x3 = (float)X[ts*G4 + 3*HH + j];
      // h window for this half (broadcast across lanes)
      const uint* hbp = hq + (step&1)*56 + half*28;
      uint4 hA = *(const uint4*)(hbp+0);
      uint4 hB = *(const uint4*)(hbp+4);
      uint4 hC = *(const uint4*)(hbp+8);
      uint4 hD = *(const uint4*)(hbp+12);
      uint4 hE = *(const uint4*)(hbp+16);
      uint4 hF = *(const uint4*)(hbp+20);
      uint  hG = hbp[24];
      I4 d;
      if (fullw) d = dot25<64>(wlds4 + baseq, hA,hB,hC,hD,hE,hF,hG);
      else       d = dot25<16>(wlds4 + baseq, hA,hB,hC,hD,hE,hF,hG);
      float a0 = (float)d.d0*sc0 + x0*0.5f;
      float a1 = (float)d.d1*sc1 + x1*0.5f;
      float a2 = (float)d.d2*sc2 + x2*0.5f;
      float a3 = (float)d.d3*sc3 + x3*0.5f;
      // sum the two dim-halves (x added half in each lane -> once total)
      a0 += __shfl_xor(a0, 1, 64);
      a1 += __shfl_xor(a1, 1, 64);
      a2 += __shfl_xor(a2, 1, 64);
      a3 += __shfl_xor(a3, 1, 64);
      // gates: rows 0..199=i, 200..399=f, 400..599=g, 600..799=o
      c = sigf(a1)*c + sigf(a0)*tanhf_fast(a2);
      float h = sigf(a3)*tanhf_fast(c);
      if (half == 0){
        hout[ts*HH + j] = h;
        int q = (int)rintf(h*127.f);
        q = q<-127?-127:(q>127?127:q);
        int bufbyte = ((step+1)&1)*224 + (j<100 ? j : 112 + (j-100));
        ((unsigned char*)hq)[bufbyte] = (unsigned char)(q & 0xff);
      }
    }
    __syncthreads();
  }
}

// ---------------- K4: token attention-score MLP ----------------
__global__ void k_attn(const float* __restrict__ hf, const float* __restrict__ hb,
    const ushort* w1, const ushort* b1, const ushort* w2, const ushort* b2,
    const ushort* w3, const ushort* b3, float* __restrict__ attns){
  __shared__ float s[2*HH];
  __shared__ float h1[HS], h2[HS];
  int t = blockIdx.x;
  for (int k=threadIdx.x;k<2*HH;k+=256)
    s[k] = (k<HH) ? hf[t*HH+k] : hb[t*HH + (k-HH)];
  __syncthreads();
  int o = threadIdx.x;
  if (o < HS){
    float acc = bf2f(b1[o]);
    const ushort* wr = w1 + o*2*HH;
    for (int k=0;k<2*HH;k+=4){
      ushort4 wv = *(const ushort4*)(wr+k);
      acc += bf2f(wv.x)*s[k] + bf2f(wv.y)*s[k+1] + bf2f(wv.z)*s[k+2] + bf2f(wv.w)*s[k+3];
    }
    h1[o] = fmaxf(acc, 0.f);
  }
  __syncthreads();
  if (o < HS){
    float acc = bf2f(b2[o]);
    const ushort* wr = w2 + o*HS;
    for (int k=0;k<HS;k+=2) acc += bf2f(wr[k])*h1[k] + bf2f(wr[k+1])*h1[k+1];
    h2[o] = fmaxf(acc, 0.f);
  }
  __syncthreads();
  if (o == 0){
    float acc = bf2f(b3[0]);
    for (int k=0;k<HS;k++) acc += bf2f(w3[k])*h2[k];
    attns[t] = acc;
  }
}

// ---------------- K5: span features + mention MLP (8 spans/block) ----------------
__global__ void k_ment(const int* __restrict__ sstart, const int* __restrict__ send,
    const int* __restrict__ tok,
    const float* __restrict__ hf, const float* __restrict__ hb,
    const ushort* __restrict__ emb, const float* __restrict__ attns,
    const ushort* wemb,
    const ushort* w1, const ushort* b1, const ushort* w2, const ushort* b2,
    const ushort* w3, const ushort* b3, float* __restrict__ si){
  __shared__ __align__(16) float G[8][GDIM];
  __shared__ float H1[8][152], H2[8][152];
  __shared__ float aw[8][WMAX];
  __shared__ int stok[8][WMAX];
  __shared__ int sst[8], sen[8], sbin[8];
  int s0 = blockIdx.x*8;
  if (threadIdx.x < 8){
    int sp = threadIdx.x;
    int st = sstart[s0+sp], en = send[s0+sp];
    sst[sp]=st; sen[sp]=en;
    int width = en - st + 1;
    sbin[sp] = binv(width);
    float lg[WMAX]; float mx = -1e30f;
    for (int wt=0; wt<WMAX; ++wt){
      int idx = st + wt; if (idx > TT-1) idx = TT-1;
      float l = (wt < width) ? attns[idx] : -1e9f;
      lg[wt] = l; mx = fmaxf(mx, l);
    }
    float den = 0.f;
    for (int wt=0; wt<WMAX; ++wt){ lg[wt] = __expf(lg[wt]-mx); den += lg[wt]; }
    float inv = 1.f/den;
    for (int wt=0; wt<WMAX; ++wt) aw[sp][wt] = lg[wt]*inv;
  }
  if (threadIdx.x < 8*WMAX){
    int sp = threadIdx.x / WMAX, wt = threadIdx.x - sp*WMAX;
    int idx = sstart[s0+sp] + wt; if (idx > TT-1) idx = TT-1;
    stok[sp][wt] = tok[idx];
  }
  __syncthreads();
  for (int i = threadIdx.x; i < 8*GDIM; i += 256){
    int sp = i / GDIM, f = i - sp*GDIM;
    int st = sst[sp], en = sen[sp];
    float v;
    if (f < HH) v = hf[st*HH + f];
    else if (f < 2*HH) v = hb[st*HH + (f-HH)];
    else if (f < 3*HH) v = hf[en*HH + (f-2*HH)];
    else if (f < 4*HH) v = hb[en*HH + (f-3*HH)];
    else if (f < 4*HH + EE){
      int e = f - 4*HH;
      float acc = 0.f;
      for (int wt=0; wt<WMAX; ++wt)
        acc += aw[sp][wt] * bf2f(emb[stok[sp][wt]*EE + e]);
      v = acc;
    } else {
      v = bf2f(wemb[sbin[sp]*FD + (f - (4*HH+EE))]);
    }
    G[sp][f] = v;
  }
  __syncthreads();
  for (int tt = threadIdx.x; tt < 8*HS; tt += 256){
    int sp = tt & 7, o = tt >> 3;
    float acc = bf2f(b1[o]);
    const ushort* wr = w1 + o*GDIM;
    for (int k=0;k<GDIM;k+=4){
      ushort4 wv = *(const ushort4*)(wr+k);
      acc += bf2f(wv.x)*G[sp][k] + bf2f(wv.y)*G[sp][k+1]
           + bf2f(wv.z)*G[sp][k+2] + bf2f(wv.w)*G[sp][k+3];
    }
    H1[sp][o] = fmaxf(acc, 0.f);
  }
  __syncthreads();
  for (int tt = threadIdx.x; tt < 8*HS; tt += 256){
    int sp = tt & 7, o = tt >> 3;
    float acc = bf2f(b2[o]);
    const ushort* wr = w2 + o*HS;
    for (int k=0;k<HS;k+=2) acc += bf2f(wr[k])*H1[sp][k] + bf2f(wr[k+1])*H1[sp][k+1];
    H2[sp][o] = fmaxf(acc, 0.f);
  }
  __syncthreads();
  if (threadIdx.x < 8){
    int sp = threadIdx.x;
    float acc = bf2f(b3[0]);
    for (int k=0;k<HS;k++) acc += bf2f(w3[k])*H2[sp][k];
    si[s0+sp] = sanit(acc);
  }
}

// ---------------- K6: top-384 + index-ordered compaction (single block) ----------------
__global__ __launch_bounds__(1024) void k_select(const float* __restrict__ si,
    const int* __restrict__ sstart, const int* __restrict__ send,
    uint* __restrict__ keysb, int* __restrict__ keep, float* __restrict__ sk,
    int* __restrict__ stk, int* __restrict__ enk){
  __shared__ uint hist[256];
  __shared__ uint sG[1024], sE[1024];
  __shared__ uint bc[2];
  int tid = threadIdx.x;
  if (tid < NK){ keep[tid]=0; sk[tid]=0.f; stk[tid]=0; enk[tid]=0; }
  for (int i=tid;i<NS;i+=1024){
    uint u = __float_as_uint(si[i]);
    uint m = (u & 0x80000000u) ? ~u : (u | 0x80000000u);  // order-preserving map
    keysb[i] = m;
  }
  __syncthreads();
  uint prefix=0, mask=0; int K = NK;
  for (int p=3;p>=0;--p){
    int sh = p*8;
    if (tid<256) hist[tid]=0;
    __syncthreads();
    for (int i=tid;i<NS;i+=1024){
      uint m = keysb[i];
      if ((m & mask) == prefix) atomicAdd(&hist[(m>>sh)&255u], 1u);
    }
    __syncthreads();
    if (tid==0){
      uint cum=0;
      bc[0]=0; bc[1]=(uint)K;
      for (int b=255; b>=0; --b){
        uint c = hist[b];
        if ((uint)K <= cum + c){ bc[0]=(uint)b; bc[1]=(uint)(K - (int)cum); break; }
        cum += c;
      }
    }
    __syncthreads();
    prefix |= bc[0] << sh;
    mask |= 0xFFu << sh;
    K = (int)bc[1];
    __syncthreads();
  }
  const uint V = prefix; const uint Eneed = (uint)K;
  int base = tid*20;
  uint cg=0, ce=0;
  for (int r=0;r<20;++r){
    uint m = keysb[base+r];
    cg += (m > V); ce += (m == V);
  }
  sG[tid]=cg; sE[tid]=ce;
  __syncthreads();
  for (int off=1; off<1024; off<<=1){
    uint aG=0,aE=0;
    if (tid>=off){ aG=sG[tid-off]; aE=sE[tid-off]; }
    __syncthreads();
    if (tid>=off){ sG[tid]+=aG; sE[tid]+=aE; }
    __syncthreads();
  }
  uint gbase = sG[tid]-cg, ebase = sE[tid]-ce;
  uint gseen=0, eseen=0;
  for (int r=0;r<20;++r){
    int i = base+r;
    uint m = keysb[i];
    if (m > V){
      uint eb = ebase+eseen; if (eb > Eneed) eb = Eneed;
      uint pos = gbase + gseen + eb;
      if (pos < NK){ keep[pos]=i; sk[pos]=si[i]; stk[pos]=sstart[i]; enk[pos]=send[i]; }
      gseen++;
    } else if (m == V){
      uint eb = ebase + eseen;
      if (eb < Eneed){
        uint pos = gbase + gseen + eb;
        if (pos < NK){ keep[pos]=i; sk[pos]=si[i]; stk[pos]=sstart[i]; enk[pos]=send[i]; }
      }
      eseen++;
    }
  }
}

// ---------------- K7: rebuild g for kept spans ----------------
__global__ void k_gk(const int* __restrict__ keep, const int* __restrict__ tok,
    const float* __restrict__ hf, const float* __restrict__ hb,
    const ushort* __restrict__ emb, const float* __restrict__ attns,
    const ushort* wemb, const int* __restrict__ sstart, const int* __restrict__ send,
    float* __restrict__ gk){
  __shared__ float aw[WMAX];
  __shared__ int stok1[WMAX];
  __shared__ int sstv, senv, sbinv;
  int b = blockIdx.x;
  if (threadIdx.x == 0){
    int s = keep[b]; s = s < 0 ? 0 : (s >= NS ? NS-1 : s);
    int st = sstart[s], en = send[s];
    sstv=st; senv=en;
    int width = en-st+1;
    sbinv = binv(width);
    float lg[WMAX]; float mx=-1e30f;
    for (int wt=0;wt<WMAX;++wt){
      int idx = st+wt; if (idx>TT-1) idx=TT-1;
      float l = (wt<width)? attns[idx] : -1e9f;
      lg[wt]=l; mx=fmaxf(mx,l);
    }
    float den=0.f;
    for (int wt=0;wt<WMAX;++wt){ lg[wt]=__expf(lg[wt]-mx); den+=lg[wt]; }
    float inv=1.f/den;
    for (int wt=0;wt<WMAX;++wt) aw[wt]=lg[wt]*inv;
  }
  if (threadIdx.x < WMAX){
    int s = keep[b]; s = s < 0 ? 0 : (s >= NS ? NS-1 : s);
    int idx = sstart[s] + threadIdx.x; if (idx>TT-1) idx=TT-1;
    stok1[threadIdx.x] = tok[idx];
  }
  __syncthreads();
  int st=sstv, en=senv;
  for (int f=threadIdx.x; f<GDIM; f+=256){
    float v;
    if (f < HH) v = hf[st*HH + f];
    else if (f < 2*HH) v = hb[st*HH + (f-HH)];
    else if (f < 3*HH) v = hf[en*HH + (f-2*HH)];
    else if (f < 4*HH) v = hb[en*HH + (f-3*HH)];
    else if (f < 4*HH + EE){
      int e = f - 4*HH;
      float acc = 0.f;
      for (int wt=0; wt<WMAX; ++wt)
        acc += aw[wt] * bf2f(emb[stok1[wt]*EE + e]);
      v = acc;
    } else {
      v = bf2f(wemb[sbinv*FD + (f - (4*HH+EE))]);
    }
    gk[b*GDIM + f] = v;
  }
}

// ---------------- K8a: P[i]=w1a.gk[i], Q[i]=w1b.gk[i]; also eps column ----------------
__global__ void k_pq(const float* __restrict__ gk, const ushort* __restrict__ w1,
                     float* __restrict__ P, float* __restrict__ Q, float* __restrict__ out){
  __shared__ __align__(16) float gi[GDIM];
  int i = blockIdx.x, which = blockIdx.y;
  for (int k=threadIdx.x;k<GDIM;k+=256) gi[k]=gk[i*GDIM+k];
  __syncthreads();
  if (which==0 && threadIdx.x==0) out[i*OUTC + NA] = 0.0f;   // eps column
  int o = threadIdx.x;
  if (o < HS){
    const ushort* wr = w1 + o*3680 + which*GDIM;
    float acc=0.f;
    for (int k=0;k<GDIM;k+=4){
      ushort4 wv = *(const ushort4*)(wr+k);
      acc += bf2f(wv.x)*gi[k]+bf2f(wv.y)*gi[k+1]+bf2f(wv.z)*gi[k+2]+bf2f(wv.w)*gi[k+3];
    }
    (which? Q : P)[i*HS+o] = acc;
  }
}

// ---------------- K8b: pair MLP (decomposed layer-1), 16 antecedents/block ----------------
__global__ void k_pair(const float* __restrict__ gk, const float* __restrict__ P,
    const float* __restrict__ Q, const float* __restrict__ sk,
    const int* __restrict__ stk, const int* __restrict__ enk,
    const ushort* w1, const ushort* b1, const ushort* w2, const ushort* b2,
    const ushort* w3, const ushort* b3, const ushort* demb, float* __restrict__ out){
  __shared__ __align__(16) float gi[GDIM];
  __shared__ float Pi[152];
  __shared__ float Dall[9*HS];
  __shared__ __align__(16) float GIJ[8][GDIM];
  __shared__ float H1[8][152], H2[8][152];
  __shared__ int jcA[16], dbA[16], vA[16];
  __shared__ float skj[16];
  int i = blockIdx.x;
  int d0 = blockIdx.y*16;
  if (i - 1 - d0 < 0){
    for (int d = threadIdx.x; d < 16; d += 256) out[i*OUTC + d0 + d] = -1e9f;
    return;
  }
  for (int k=threadIdx.x;k<GDIM;k+=256) gi[k]=gk[i*GDIM+k];
  for (int o=threadIdx.x;o<HS;o+=256) Pi[o]=P[i*HS+o];
  if (threadIdx.x < 16){
    int dcol = d0 + threadIdx.x;
    int j = i - 1 - dcol;
    int jc = j<0?0:j;
    vA[threadIdx.x]=(j>=0);
    jcA[threadIdx.x]=jc;
    dbA[threadIdx.x]=binv(enk[i]-stk[jc]);
    skj[threadIdx.x]=sk[jc];
  }
  for (int tt=threadIdx.x; tt<9*HS; tt+=256){
    int o = tt/9, b = tt - (tt/9)*9;
    float acc = bf2f(b1[o]);
    const ushort* wr = w1 + o*3680 + 3660;
    const ushort* de = demb + b*FD;
    for (int k=0;k<FD;k++) acc += bf2f(wr[k])*bf2f(de[k]);
    Dall[b*HS+o] = acc;
  }
  __syncthreads();
  float ski = sk[i];
  for (int dt=0; dt<2; ++dt){
    if (i - 1 - (d0 + dt*8) < 0){
      if (threadIdx.x < 8) out[i*OUTC + d0 + dt*8 + threadIdx.x] = -1e9f;
      continue;
    }
    __syncthreads();
    for (int idx=threadIdx.x; idx<8*GDIM; idx+=256){
      int dd = idx / GDIM, k = idx - dd*GDIM;
      GIJ[dd][k] = gi[k]*gk[jcA[dt*8+dd]*GDIM + k];
    }
    __syncthreads();
    {
      int dd = threadIdx.x & 7, og = threadIdx.x >> 3;
      for (int o=og; o<HS; o+=32){
        const ushort* wr = w1 + o*3680 + 2*GDIM;
        float acc = 0.f;
        for (int k=0;k<GDIM;k+=4){
          ushort4 wv = *(const ushort4*)(wr+k);
          float4 gv = *(const float4*)&GIJ[dd][k];
          acc += bf2f(wv.x)*gv.x + bf2f(wv.y)*gv.y + bf2f(wv.z)*gv.z + bf2f(wv.w)*gv.w;
        }
        int d = dt*8+dd;
        acc += Pi[o] + Q[jcA[d]*HS+o] + Dall[dbA[d]*HS+o];
        H1[dd][o] = fmaxf(acc, 0.f);
      }
    }
    __syncthreads();
    {
      int dd = threadIdx.x & 7, og = threadIdx.x >> 3;
      for (int o=og;o<HS;o+=32){
        float acc = bf2f(b2[o]);
        const ushort* wr = w2 + o*HS;
        for (int k=0;k<HS;k+=2) acc += bf2f(wr[k])*H1[dd][k] + bf2f(wr[k+1])*H1[dd][k+1];
        H2[dd][o]=fmaxf(acc,0.f);
      }
    }
    __syncthreads();
    if (threadIdx.x < 8){
      int dd = threadIdx.x;
      float acc = bf2f(b3[0]);
      for (int k=0;k<HS;k++) acc += bf2f(w3[k])*H2[dd][k];
      int d = dt*8+dd;
      float raw = sanit(ski + skj[d] + acc);
      float v = vA[d] ? raw : -1e9f;
      out[i*OUTC + d0 + d] = v;
    }
  }
}

extern "C" void kernel_launch(void* const* d_in, const int* in_sizes, int n_in,
                              void* d_out, int out_size, void* d_ws, size_t ws_size,
                              hipStream_t stream){
  (void)in_sizes; (void)n_in; (void)out_size; (void)ws_size;
  const int*    tok   = (const int*)d_in[0];
  const int*    sst   = (const int*)d_in[1];
  const int*    sen   = (const int*)d_in[2];
  const ushort* emb   = (const ushort*)d_in[3];
  const ushort* wih_f = (const ushort*)d_in[4];
  const ushort* whh_f = (const ushort*)d_in[5];
  const ushort* b_f   = (const ushort*)d_in[6];
  const ushort* wih_b = (const ushort*)d_in[7];
  const ushort* whh_b = (const ushort*)d_in[8];
  const ushort* b_b   = (const ushort*)d_in[9];
  const ushort* aw1=(const ushort*)d_in[10]; const ushort* ab1=(const ushort*)d_in[11];
  const ushort* aw2=(const ushort*)d_in[12]; const ushort* ab2=(const ushort*)d_in[13];
  const ushort* aw3=(const ushort*)d_in[14]; const ushort* ab3=(const ushort*)d_in[15];
  const ushort* wemb=(const ushort*)d_in[16];
  const ushort* mw1=(const ushort*)d_in[17]; const ushort* mb1=(const ushort*)d_in[18];
  const ushort* mw2=(const ushort*)d_in[19]; const ushort* mb2=(const ushort*)d_in[20];
  const ushort* mw3=(const ushort*)d_in[21]; const ushort* mb3=(const ushort*)d_in[22];
  const ushort* demb=(const ushort*)d_in[23];
  const ushort* pw1=(const ushort*)d_in[24]; const ushort* pb1=(const ushort*)d_in[25];
  const ushort* pw2=(const ushort*)d_in[26]; const ushort* pb2=(const ushort*)d_in[27];
  const ushort* pw3=(const ushort*)d_in[28]; const ushort* pb3=(const ushort*)d_in[29];
  float* out = (float*)d_out;

  float* ws     = (float*)d_ws;
  float* hfw    = ws;                       // 409600
  float* hbw    = hfw + TT*HH;              // 409600
  float* attns  = hbw + TT*HH;              // 2048
  float* si     = attns + TT;               // 20480
  float* sk     = si + NS;                  // 384
  float* Pb     = sk + NK;                  // 57600
  float* Qb     = Pb + NK*HS;               // 57600
  float* gkw    = Qb + NK*HS;               // 468480
  _Float16* Xf  = (_Float16*)(gkw + NK*GDIM); // 1638400 halves
  _Float16* Xb  = Xf + TT*G4;                 // 1638400 halves
  int*   keep   = (int*)(Xb + TT*G4);       // 384
  int*   stk    = keep + NK;                // 384
  int*   enk    = stk + NK;                 // 384
  uint*  keysb  = (uint*)(enk + NK);        // 20480
  // total ~12.34 MB of d_ws

  k_xproj<<<TT/4,256,0,stream>>>(tok, emb, wih_f, b_f, wih_b, b_b, Xf, Xb);
  k_lstm<<<2,448,0,stream>>>(whh_f, whh_b, Xf, Xb, hfw, hbw);
  k_attn<<<TT,256,0,stream>>>(hfw,hbw,aw1,ab1,aw2,ab2,aw3,ab3,attns);
  k_ment<<<NS/8,256,0,stream>>>(sst,sen,tok,hfw,hbw,emb,attns,wemb,mw1,mb1,mw2,mb2,mw3,mb3,si);
  k_select<<<1,1024,0,stream>>>(si,sst,sen,keysb,keep,sk,stk,enk);
  k_gk<<<NK,256,0,stream>>>(keep,tok,hfw,hbw,emb,attns,wemb,sst,sen,gkw);
  k_pq<<<dim3(NK,2),256,0,stream>>>(gkw,pw1,Pb,Qb,out);
  k_pair<<<dim3(NK,8),256,0,stream>>>(gkw,Pb,Qb,sk,stk,enk,pw1,pb1,pw2,pb2,pw3,pb3,demb,out);
}